// Round 10
// baseline (70.489 us; speedup 1.0000x reference)
//
#include <hip/hip_runtime.h>

// RBF network, SEPARABLE-GRID form, wave-split contraction, packed-f32 dot,
// 2 points/lane, LDS-staged weights.
// centers = meshgrid(g1[20],g2[5],g3[20],'ij'), beta = const ->
//   exp2(-b|x-c|^2) = e_i(x0)*f_j(x1)*g_k(x2),  c = i*100+j*20+k, b=beta*log2e
// (common factor exp2(-b|x|^2) cancels in num/den and is dropped)
//   den = (sum e)(sum f)(sum g)
//   num = sum_m (f_j*g_k) * (sum_i wt[m][i]*e_i)     m = j*20+k
//
// Round-10: rounds 8/9 proved main is LOAD-LATENCY-bound (halving VALU insts
// twice moved <1us each; ~280 cyc stall per w-row = un-overlapped L2 latency,
// register pressure limits row prefetch depth). Fix: stage the whole 8 KB
// weight table into LDS once per block; rows padded 20->24 floats so every
// row base is 16B-aligned -> ds_read_b128 with immediate offsets off ONE
// base VGPR. Uniform-address LDS reads broadcast (conflict-free), ~120 cyc
// latency, deeply pipelined by the compiler vs the 52 cyc of pk-math per row.
// Geometry unchanged from R9: 1024 blocks x 4 waves, wave w takes k in
// [5w,5w+5), 2 points/lane sharing every weight row.

typedef float v2f __attribute__((ext_vector_type(2)));

__global__ __launch_bounds__(256) void rbf_precompute(
        const float* __restrict__ centers,
        const float* __restrict__ beta,
        const float* __restrict__ lin_w,
        float* __restrict__ tab, int C) {
    int t = blockIdx.x * blockDim.x + threadIdx.x;
    if (t < C) {                       // transpose: tab[m*20+i] = lin_w[i*100+m]
        int i = t / 100;
        int m = t - i * 100;
        tab[m * 20 + i] = lin_w[t];
    }
    if (blockIdx.x == 0 && threadIdx.x < 45) {   // 45 grid-line constants
        const float LOG2E = 1.4426950408889634f;
        float b = beta[0] * LOG2E;
        int u = threadIdx.x;
        float gv;
        int k1o, k0o, idx;
        if (u < 20)      { idx = u;      gv = centers[3*(idx*100) + 0]; k1o = 2000; k0o = 2020; }
        else if (u < 25) { idx = u - 20; gv = centers[3*(idx*20)  + 1]; k1o = 2040; k0o = 2045; }
        else             { idx = u - 25; gv = centers[3*idx       + 2]; k1o = 2050; k0o = 2070; }
        tab[k1o + idx] = 2.0f * b * gv;
        tab[k0o + idx] = -b * gv * gv;
    }
}

__global__ __launch_bounds__(256, 4) void rbf_main(
        const float* __restrict__ x,
        const float* __restrict__ tab,
        float* __restrict__ out,
        int n) {
    // weight rows padded to 24 floats (96 B, 16B-aligned) -> ds_read_b128
    __shared__ float wlds[100 * 24];
    __shared__ float red[4][4][64];

    const int tid  = threadIdx.x;
    const int lane = tid & 63;
    const int wv   = __builtin_amdgcn_readfirstlane(tid >> 6);  // 0..3

    // cooperative stage: tab[m*20+i] -> wlds[m*24+i]  (8 elems/thread)
    #pragma unroll
    for (int idx = tid; idx < 2000; idx += 256) {
        int m = idx / 20;
        int i = idx - m * 20;
        wlds[m * 24 + i] = tab[idx];
    }

    const int pA = blockIdx.x * 128 + lane;       // 128 points per block
    const int pB = pA + 64;
    const bool vA = (pA < n), vB = (pB < n);

    float a0 = 0.f, a1 = 0.f, a2 = 0.f, b0 = 0.f, b1 = 0.f, b2 = 0.f;
    if (vA) { a0 = x[3*pA]; a1 = x[3*pA+1]; a2 = x[3*pA+2]; }
    if (vB) { b0 = x[3*pB]; b1 = x[3*pB+1]; b2 = x[3*pB+2]; }

    const float* k1e = tab + 2000;  const float* k0e = tab + 2020;
    const float* k1f = tab + 2040;  const float* k0f = tab + 2045;
    const float* k1g = tab + 2050;  const float* k0g = tab + 2070;

    const int kbase = wv * 5;                     // this wave's k-slice

    // exps overlap the LDS staging before the barrier
    v2f EA[10], EB[10];
    #pragma unroll
    for (int i2 = 0; i2 < 10; ++i2) {
        EA[i2].x = __builtin_amdgcn_exp2f(fmaf(k1e[2*i2],   a0, k0e[2*i2]));
        EA[i2].y = __builtin_amdgcn_exp2f(fmaf(k1e[2*i2+1], a0, k0e[2*i2+1]));
        EB[i2].x = __builtin_amdgcn_exp2f(fmaf(k1e[2*i2],   b0, k0e[2*i2]));
        EB[i2].y = __builtin_amdgcn_exp2f(fmaf(k1e[2*i2+1], b0, k0e[2*i2+1]));
    }
    float fA[5], fB[5], gA[5], gB[5];
    #pragma unroll
    for (int j = 0; j < 5; ++j) {
        fA[j] = __builtin_amdgcn_exp2f(fmaf(k1f[j], a1, k0f[j]));
        fB[j] = __builtin_amdgcn_exp2f(fmaf(k1f[j], b1, k0f[j]));
    }
    #pragma unroll
    for (int kk = 0; kk < 5; ++kk) {
        gA[kk] = __builtin_amdgcn_exp2f(fmaf(k1g[kbase+kk], a2, k0g[kbase+kk]));
        gB[kk] = __builtin_amdgcn_exp2f(fmaf(k1g[kbase+kk], b2, k0g[kbase+kk]));
    }

    __syncthreads();                              // staging complete

    // 25 m-rows from LDS; all row bases = kbase*24*4 + imm -> immediate offsets
    float numA = 0.f, numB = 0.f;
    #pragma unroll
    for (int j = 0; j < 5; ++j) {
        #pragma unroll
        for (int kk = 0; kk < 5; ++kk) {
            const float4* wr = (const float4*)&wlds[(j*20 + kbase + kk) * 24];
            float4 w0 = wr[0], w1 = wr[1], w2 = wr[2], w3 = wr[3], w4 = wr[4];
            v2f W[10] = { {w0.x,w0.y}, {w0.z,w0.w}, {w1.x,w1.y}, {w1.z,w1.w},
                          {w2.x,w2.y}, {w2.z,w2.w}, {w3.x,w3.y}, {w3.z,w3.w},
                          {w4.x,w4.y}, {w4.z,w4.w} };
            v2f tA2 = W[0] * EA[0];
            v2f tB2 = W[0] * EB[0];
            #pragma unroll
            for (int i2 = 1; i2 < 10; ++i2) {
                tA2 = __builtin_elementwise_fma(W[i2], EA[i2], tA2);
                tB2 = __builtin_elementwise_fma(W[i2], EB[i2], tB2);
            }
            numA = fmaf(tA2.x + tA2.y, fA[j] * gA[kk], numA);
            numB = fmaf(tB2.x + tB2.y, fB[j] * gB[kk], numB);
        }
    }

    float sgA = 0.f, sgB = 0.f;
    #pragma unroll
    for (int kk = 0; kk < 5; ++kk) { sgA += gA[kk]; sgB += gB[kk]; }

    // cross-wave reduce: [wave][val][lane], lane-stride-1, conflict-free
    if (wv > 0) {
        red[wv][0][lane] = numA;  red[wv][1][lane] = sgA;
        red[wv][2][lane] = numB;  red[wv][3][lane] = sgB;
    }
    __syncthreads();
    if (wv == 0) {
        #pragma unroll
        for (int w2i = 1; w2i < 4; ++w2i) {
            numA += red[w2i][0][lane];  sgA += red[w2i][1][lane];
            numB += red[w2i][2][lane];  sgB += red[w2i][3][lane];
        }
        v2f seA2 = EA[0], seB2 = EB[0];
        #pragma unroll
        for (int i2 = 1; i2 < 10; ++i2) { seA2 += EA[i2]; seB2 += EB[i2]; }
        float seA = seA2.x + seA2.y, seB = seB2.x + seB2.y;
        float sfA = 0.f, sfB = 0.f;
        #pragma unroll
        for (int j = 0; j < 5; ++j) { sfA += fA[j]; sfB += fB[j]; }
        if (vA) out[pA] = numA / (seA * sfA * sgA);
        if (vB) out[pB] = numB / (seB * sfB * sgB);
    }
}

extern "C" void kernel_launch(void* const* d_in, const int* in_sizes, int n_in,
                              void* d_out, int out_size, void* d_ws, size_t ws_size,
                              hipStream_t stream) {
    const float* x       = (const float*)d_in[0];   // (N,3)
    const float* centers = (const float*)d_in[1];   // (C,3) — separable grid
    const float* beta    = (const float*)d_in[2];   // (C,) — constant
    const float* lin_w   = (const float*)d_in[3];   // (1,C)
    float* out = (float*)d_out;                     // (N,1) fp32
    float* tab = (float*)d_ws;                      // wt[2000] + consts[90]

    int C = in_sizes[2];                            // 2000
    int n = in_sizes[0] / 3;                        // 131072

    int pre_blocks = (C + 255) / 256;
    rbf_precompute<<<pre_blocks, 256, 0, stream>>>(centers, beta, lin_w, tab, C);

    int main_blocks = (n + 127) / 128;              // 128 points per block
    rbf_main<<<main_blocks, 256, 0, stream>>>(x, tab, out, n);
}

// Round 11
// 68.334 us; speedup vs baseline: 1.0315x; 1.0315x over previous
//
#include <hip/hip_runtime.h>

// RBF network, SEPARABLE-GRID form — SINGLE FUSED KERNEL.
// centers = meshgrid(g1[20],g2[5],g3[20],'ij'), beta = const ->
//   exp2(-b|x-c|^2) = e_i(x0)*f_j(x1)*g_k(x2),  c = i*100+j*20+k, b=beta*log2e
// (common factor exp2(-b|x|^2) cancels in num/den and is dropped)
//   den = (sum e)(sum f)(sum g)
//   num = sum_m (f_j*g_k) * (sum_i wt[m][i]*e_i)     m = j*20+k
//
// Round-11: rounds 8/9/10 proved the contraction loop is NOT the bottleneck
// (halving VALU insts, 2x ILP, LDS weights: each <2us delta). The ~16us
// controllable slice is dominated by dispatch/drain overhead of the serial
// two-kernel chain (launch ~4-6us each + dependency gap), not compute.
// Fix: fuse everything into ONE kernel. Each block:
//   1. derives the 45 grid-line constants from centers/beta (45 threads->LDS),
//   2. transposes lin_w straight into padded LDS (coalesced 8KB read;
//      rows m padded 20->24 floats, 16B-aligned -> ds_read_b128),
//   3. runs the R9 math: 4 waves, wave w takes k in [5w,5w+5),
//      2 points/lane sharing every weight row, v_pk_fma_f32 dot.
// No precompute kernel, no tab round-trip, no inter-kernel serialization.

typedef float v2f __attribute__((ext_vector_type(2)));

__global__ __launch_bounds__(256, 4) void rbf_fused(
        const float* __restrict__ x,
        const float* __restrict__ centers,
        const float* __restrict__ beta,
        const float* __restrict__ lin_w,
        float* __restrict__ out,
        int n) {
    __shared__ float wlds[100 * 24];   // wt[m][i], rows padded to 24 floats
    __shared__ float cst[90];          // k1e[20]@0 k0e@20 k1f@40 k0f@45 k1g@50 k0g@70
    __shared__ float red[4][4][64];

    const int tid  = threadIdx.x;
    const int lane = tid & 63;
    const int wv   = __builtin_amdgcn_readfirstlane(tid >> 6);  // 0..3

    // --- per-block setup (replaces the old precompute kernel) ---
    // grid-line constants from centers/beta
    if (tid < 45) {
        const float LOG2E = 1.4426950408889634f;
        float b = beta[0] * LOG2E;
        float gv;
        int k1o, k0o, idx;
        if (tid < 20)      { idx = tid;      gv = centers[3*(idx*100) + 0]; k1o = 0;  k0o = 20; }
        else if (tid < 25) { idx = tid - 20; gv = centers[3*(idx*20)  + 1]; k1o = 40; k0o = 45; }
        else               { idx = tid - 25; gv = centers[3*idx       + 2]; k1o = 50; k0o = 70; }
        cst[k1o + idx] = 2.0f * b * gv;
        cst[k0o + idx] = -b * gv * gv;
    }
    // transpose lin_w[i*100+m] -> wlds[m*24+i]  (coalesced global read)
    #pragma unroll
    for (int idx = tid; idx < 2000; idx += 256) {
        int i = idx / 100;
        int m = idx - i * 100;
        wlds[m * 24 + i] = lin_w[idx];
    }

    const int pA = blockIdx.x * 128 + lane;       // 128 points per block
    const int pB = pA + 64;
    const bool vA = (pA < n), vB = (pB < n);

    float a0 = 0.f, a1 = 0.f, a2 = 0.f, b0 = 0.f, b1 = 0.f, b2 = 0.f;
    if (vA) { a0 = x[3*pA]; a1 = x[3*pA+1]; a2 = x[3*pA+2]; }
    if (vB) { b0 = x[3*pB]; b1 = x[3*pB+1]; b2 = x[3*pB+2]; }

    __syncthreads();                              // setup complete

    const int kbase = wv * 5;                     // this wave's k-slice

    // exps: constants broadcast from LDS (uniform address -> conflict-free)
    v2f EA[10], EB[10];
    #pragma unroll
    for (int i2 = 0; i2 < 10; ++i2) {
        float k1a = cst[2*i2],   k0a = cst[20 + 2*i2];
        float k1b = cst[2*i2+1], k0b = cst[20 + 2*i2+1];
        EA[i2].x = __builtin_amdgcn_exp2f(fmaf(k1a, a0, k0a));
        EA[i2].y = __builtin_amdgcn_exp2f(fmaf(k1b, a0, k0b));
        EB[i2].x = __builtin_amdgcn_exp2f(fmaf(k1a, b0, k0a));
        EB[i2].y = __builtin_amdgcn_exp2f(fmaf(k1b, b0, k0b));
    }
    float fA[5], fB[5], gA[5], gB[5];
    #pragma unroll
    for (int j = 0; j < 5; ++j) {
        float k1 = cst[40 + j], k0 = cst[45 + j];
        fA[j] = __builtin_amdgcn_exp2f(fmaf(k1, a1, k0));
        fB[j] = __builtin_amdgcn_exp2f(fmaf(k1, b1, k0));
    }
    #pragma unroll
    for (int kk = 0; kk < 5; ++kk) {
        float k1 = cst[50 + kbase + kk], k0 = cst[70 + kbase + kk];
        gA[kk] = __builtin_amdgcn_exp2f(fmaf(k1, a2, k0));
        gB[kk] = __builtin_amdgcn_exp2f(fmaf(k1, b2, k0));
    }

    // 25 m-rows from LDS; each row feeds BOTH points (40 pk-MACs / row)
    float numA = 0.f, numB = 0.f;
    #pragma unroll
    for (int j = 0; j < 5; ++j) {
        #pragma unroll
        for (int kk = 0; kk < 5; ++kk) {
            const float4* wr = (const float4*)&wlds[(j*20 + kbase + kk) * 24];
            float4 w0 = wr[0], w1 = wr[1], w2 = wr[2], w3 = wr[3], w4 = wr[4];
            v2f W[10] = { {w0.x,w0.y}, {w0.z,w0.w}, {w1.x,w1.y}, {w1.z,w1.w},
                          {w2.x,w2.y}, {w2.z,w2.w}, {w3.x,w3.y}, {w3.z,w3.w},
                          {w4.x,w4.y}, {w4.z,w4.w} };
            v2f tA2 = W[0] * EA[0];
            v2f tB2 = W[0] * EB[0];
            #pragma unroll
            for (int i2 = 1; i2 < 10; ++i2) {
                tA2 = __builtin_elementwise_fma(W[i2], EA[i2], tA2);
                tB2 = __builtin_elementwise_fma(W[i2], EB[i2], tB2);
            }
            numA = fmaf(tA2.x + tA2.y, fA[j] * gA[kk], numA);
            numB = fmaf(tB2.x + tB2.y, fB[j] * gB[kk], numB);
        }
    }

    float sgA = 0.f, sgB = 0.f;
    #pragma unroll
    for (int kk = 0; kk < 5; ++kk) { sgA += gA[kk]; sgB += gB[kk]; }

    // cross-wave reduce: [wave][val][lane], lane-stride-1, conflict-free
    if (wv > 0) {
        red[wv][0][lane] = numA;  red[wv][1][lane] = sgA;
        red[wv][2][lane] = numB;  red[wv][3][lane] = sgB;
    }
    __syncthreads();
    if (wv == 0) {
        #pragma unroll
        for (int w2i = 1; w2i < 4; ++w2i) {
            numA += red[w2i][0][lane];  sgA += red[w2i][1][lane];
            numB += red[w2i][2][lane];  sgB += red[w2i][3][lane];
        }
        v2f seA2 = EA[0], seB2 = EB[0];
        #pragma unroll
        for (int i2 = 1; i2 < 10; ++i2) { seA2 += EA[i2]; seB2 += EB[i2]; }
        float seA = seA2.x + seA2.y, seB = seB2.x + seB2.y;
        float sfA = 0.f, sfB = 0.f;
        #pragma unroll
        for (int j = 0; j < 5; ++j) { sfA += fA[j]; sfB += fB[j]; }
        if (vA) out[pA] = numA / (seA * sfA * sgA);
        if (vB) out[pB] = numB / (seB * sfB * sgB);
    }
}

extern "C" void kernel_launch(void* const* d_in, const int* in_sizes, int n_in,
                              void* d_out, int out_size, void* d_ws, size_t ws_size,
                              hipStream_t stream) {
    const float* x       = (const float*)d_in[0];   // (N,3)
    const float* centers = (const float*)d_in[1];   // (C,3) — separable grid
    const float* beta    = (const float*)d_in[2];   // (C,) — constant
    const float* lin_w   = (const float*)d_in[3];   // (1,C)
    float* out = (float*)d_out;                     // (N,1) fp32

    int n = in_sizes[0] / 3;                        // 131072

    int main_blocks = (n + 127) / 128;              // 128 points per block
    rbf_fused<<<main_blocks, 256, 0, stream>>>(x, centers, beta, lin_w, out, n);
}